// Round 1
// baseline (2268.298 us; speedup 1.0000x reference)
//
#include <hip/hip_runtime.h>
#include <hip/hip_bf16.h>

#define N_NODES 100000
#define N_EDGES 1600000
#define HEADS 4
#define CHN 32
#define HID 128
#define LAYERS 4
#define IN_F 8
#define ED_F 6
#define OUT_F 256
#define NEG_SLOPE 0.2f

__device__ __forceinline__ float elu_f(float x) {
    return x > 0.f ? x : expm1f(x);
}

// ---------------- CSR build ----------------

__global__ void hist_kernel(const int* __restrict__ dst, int* __restrict__ fill) {
    int e = blockIdx.x * blockDim.x + threadIdx.x;
    if (e < N_EDGES) atomicAdd(&fill[dst[e]], 1);
}

__global__ void scan1_kernel(const int* __restrict__ cnt, int* __restrict__ bsum) {
    __shared__ int sd[256];
    int t = threadIdx.x;
    int base = blockIdx.x * 1024 + t * 4;
    int s = 0;
#pragma unroll
    for (int j = 0; j < 4; ++j) {
        int i = base + j;
        if (i < N_NODES) s += cnt[i];
    }
    sd[t] = s;
    for (int off = 128; off > 0; off >>= 1) {
        __syncthreads();
        if (t < off) sd[t] += sd[t + off];
    }
    if (t == 0) bsum[blockIdx.x] = sd[0];
}

__global__ void scan2_kernel(int* __restrict__ bsum, int* __restrict__ rowptr, int nb) {
    // single thread: nb ~ 98 iterations
    int run = 0;
    for (int b = 0; b < nb; ++b) {
        int v = bsum[b];
        bsum[b] = run;
        run += v;
    }
    rowptr[N_NODES] = run;
}

__global__ void scan3_kernel(const int* __restrict__ cnt, const int* __restrict__ bsum,
                             int* __restrict__ rowptr) {
    __shared__ int sd[256];
    int t = threadIdx.x;
    int base = blockIdx.x * 1024 + t * 4;
    int v[4];
#pragma unroll
    for (int j = 0; j < 4; ++j) {
        int i = base + j;
        v[j] = (i < N_NODES) ? cnt[i] : 0;
    }
    int s = v[0] + v[1] + v[2] + v[3];
    sd[t] = s;
    __syncthreads();
    for (int off = 1; off < 256; off <<= 1) {
        int xv = (t >= off) ? sd[t - off] : 0;
        __syncthreads();
        sd[t] += xv;
        __syncthreads();
    }
    int excl = sd[t] - s + bsum[blockIdx.x];
    int pre = 0;
#pragma unroll
    for (int j = 0; j < 4; ++j) {
        int i = base + j;
        if (i < N_NODES) rowptr[i] = excl + pre;
        pre += v[j];
    }
}

__global__ void fill_kernel(const int* __restrict__ src, const int* __restrict__ dst,
                            const int* __restrict__ rowptr, int* __restrict__ fill,
                            int* __restrict__ csrsrc, int* __restrict__ csreid) {
    int e = blockIdx.x * blockDim.x + threadIdx.x;
    if (e >= N_EDGES) return;
    int d = dst[e];
    int p = rowptr[d] + atomicAdd(&fill[d], 1);
    csrsrc[p] = src[e];
    csreid[p] = e;
}

// loop_attr = mean of incoming edge_attr per node (0 if no incoming edges)
__global__ void lattr_kernel(const int* __restrict__ rowptr, const int* __restrict__ csreid,
                             const float* __restrict__ eattr, float* __restrict__ lattr) {
    int gid = blockIdx.x * blockDim.x + threadIdx.x;
    if (gid >= N_NODES * ED_F) return;
    int n = gid / ED_F;
    int d = gid - n * ED_F;
    int rp0 = rowptr[n], rp1 = rowptr[n + 1];
    float s = 0.f;
    for (int p = rp0; p < rp1; ++p) s += eattr[(size_t)csreid[p] * ED_F + d];
    int deg = rp1 - rp0;
    lattr[gid] = s / (float)(deg > 0 ? deg : 1);
}

// ---------------- input MLP: h0 = ELU(x @ W_in + b_in) ----------------

__global__ void in_kernel(const float* __restrict__ x, const float* __restrict__ Wi,
                          const float* __restrict__ bi, float* __restrict__ h0) {
    int gid = blockIdx.x * blockDim.x + threadIdx.x;
    if (gid >= N_NODES * HID) return;
    int n = gid >> 7, j = gid & 127;
    float acc = bi[j];
#pragma unroll
    for (int k = 0; k < IN_F; ++k) acc = fmaf(x[n * IN_F + k], Wi[k * HID + j], acc);
    h0[gid] = elu_f(acc);
}

// ---------------- per-layer node transforms xl = h@Wl+bl, xr = h@Wr+br ----------------

__global__ __launch_bounds__(128) void xlr_kernel(
    const float* __restrict__ h, const float* __restrict__ Wl, const float* __restrict__ bl,
    const float* __restrict__ Wr, const float* __restrict__ br,
    float* __restrict__ xl, float* __restrict__ xr) {
    __shared__ float hs[16][HID];
    int t = threadIdx.x;
    int r0 = blockIdx.x * 16;
#pragma unroll
    for (int r = 0; r < 16; ++r) hs[r][t] = h[(size_t)(r0 + r) * HID + t];
    __syncthreads();
    float accl[16], accr[16];
    float blv = bl[t], brv = br[t];
#pragma unroll
    for (int r = 0; r < 16; ++r) { accl[r] = blv; accr[r] = brv; }
    for (int k = 0; k < HID; ++k) {
        float wl = Wl[k * HID + t];
        float wr = Wr[k * HID + t];
#pragma unroll
        for (int r = 0; r < 16; ++r) {
            float hv = hs[r][k];
            accl[r] = fmaf(hv, wl, accl[r]);
            accr[r] = fmaf(hv, wr, accr[r]);
        }
    }
#pragma unroll
    for (int r = 0; r < 16; ++r) {
        xl[(size_t)(r0 + r) * HID + t] = accl[r];
        xr[(size_t)(r0 + r) * HID + t] = accr[r];
    }
}

// ---------------- fused edge kernel: scores + segment softmax + aggregate + LN ----------------
// one wave (64 threads) per node; lane l owns channels 2l, 2l+1 (same head h = l>>4)

__device__ __forceinline__ float edge_ex(const float* __restrict__ eat,
                                         const float* __restrict__ xlrow,
                                         const float* we0, const float* we1,
                                         float at0, float at1, float xr0, float xr1,
                                         float2* xls_out) {
    float ea0 = 0.f, ea1 = 0.f;
#pragma unroll
    for (int d = 0; d < ED_F; ++d) {
        float a = eat[d];
        ea0 = fmaf(a, we0[d], ea0);
        ea1 = fmaf(a, we1[d], ea1);
    }
    float2 xls = *(const float2*)xlrow;
    float m0 = xls.x + xr0 + ea0;
    float m1 = xls.y + xr1 + ea1;
    m0 = m0 > 0.f ? m0 : NEG_SLOPE * m0;
    m1 = m1 > 0.f ? m1 : NEG_SLOPE * m1;
    float t = m0 * at0 + m1 * at1;
    // reduce across the 16 lanes of this head (32 channels)
    t += __shfl_xor(t, 1);
    t += __shfl_xor(t, 2);
    t += __shfl_xor(t, 4);
    t += __shfl_xor(t, 8);
    *xls_out = xls;
    return expf(t);   // no max-subtraction: scores bounded ~|7|, mathematically identical
}

__global__ __launch_bounds__(64) void edge_kernel(
    const float* __restrict__ xl, const float* __restrict__ xr,
    const float* __restrict__ hcur, float* __restrict__ hnext,
    const int* __restrict__ rowptr, const int* __restrict__ csrsrc,
    const int* __restrict__ csreid,
    const float* __restrict__ eattr, const float* __restrict__ lattr,
    const float* __restrict__ We, const float* __restrict__ att,
    const float* __restrict__ bias_l, const float* __restrict__ lnw,
    const float* __restrict__ lnb) {
    int v = blockIdx.x;
    int lane = threadIdx.x;
    int c0 = lane * 2;

    float we0[ED_F], we1[ED_F];
#pragma unroll
    for (int d = 0; d < ED_F; ++d) {
        we0[d] = We[d * HID + c0];
        we1[d] = We[d * HID + c0 + 1];
    }
    float at0 = att[c0], at1 = att[c0 + 1];
    float xr0 = xr[(size_t)v * HID + c0];
    float xr1 = xr[(size_t)v * HID + c0 + 1];
    int rp0 = rowptr[v], rp1 = rowptr[v + 1];

    // ---- pass 1: denom = sum exp(score) over incoming edges + self loop
    float2 xlv;
    float ex_self = edge_ex(lattr + (size_t)v * ED_F, xl + (size_t)v * HID + c0,
                            we0, we1, at0, at1, xr0, xr1, &xlv);
    float denom = ex_self;
    for (int p = rp0; p < rp1; ++p) {
        int s = csrsrc[p];
        int eid = csreid[p];
        float2 xls;
        denom += edge_ex(eattr + (size_t)eid * ED_F, xl + (size_t)s * HID + c0,
                         we0, we1, at0, at1, xr0, xr1, &xls);
    }
    float rd = 1.f / denom;

    // ---- pass 2: out = sum alpha * xl[src]
    float a_self = ex_self * rd;
    float acc0 = a_self * xlv.x;
    float acc1 = a_self * xlv.y;
    for (int p = rp0; p < rp1; ++p) {
        int s = csrsrc[p];
        int eid = csreid[p];
        float2 xls;
        float ex = edge_ex(eattr + (size_t)eid * ED_F, xl + (size_t)s * HID + c0,
                           we0, we1, at0, at1, xr0, xr1, &xls);
        float a = ex * rd;
        acc0 = fmaf(a, xls.x, acc0);
        acc1 = fmaf(a, xls.y, acc1);
    }

    // ---- epilogue: bias + residual + LayerNorm + ELU
    float res0 = hcur[(size_t)v * HID + c0];
    float res1 = hcur[(size_t)v * HID + c0 + 1];
    float y0 = acc0 + bias_l[c0] + res0;
    float y1 = acc1 + bias_l[c0 + 1] + res1;
    float s = y0 + y1;
    float sq = y0 * y0 + y1 * y1;
#pragma unroll
    for (int off = 1; off < 64; off <<= 1) {
        s += __shfl_xor(s, off);
        sq += __shfl_xor(sq, off);
    }
    float mu = s * (1.f / HID);
    float var = sq * (1.f / HID) - mu * mu;
    float rstd = rsqrtf(var + 1e-5f);
    float n0 = (y0 - mu) * rstd * lnw[c0] + lnb[c0];
    float n1 = (y1 - mu) * rstd * lnw[c0 + 1] + lnb[c0 + 1];
    float2 o;
    o.x = elu_f(n0);
    o.y = elu_f(n1);
    *(float2*)(hnext + (size_t)v * HID + c0) = o;
}

// ---------------- output GEMM: out = h @ W_out + b_out ----------------

__global__ __launch_bounds__(256) void out_kernel(const float* __restrict__ h,
                                                  const float* __restrict__ Wo,
                                                  const float* __restrict__ bo,
                                                  float* __restrict__ out) {
    __shared__ float hs[16][HID];
    int t = threadIdx.x;
    int r0 = blockIdx.x * 16;
    for (int idx = t; idx < 16 * HID; idx += 256)
        hs[idx >> 7][idx & 127] = h[(size_t)r0 * HID + idx];
    __syncthreads();
    float acc[16];
    float bv = bo[t];
#pragma unroll
    for (int r = 0; r < 16; ++r) acc[r] = bv;
    for (int k = 0; k < HID; ++k) {
        float w = Wo[k * OUT_F + t];
#pragma unroll
        for (int r = 0; r < 16; ++r) acc[r] = fmaf(hs[r][k], w, acc[r]);
    }
#pragma unroll
    for (int r = 0; r < 16; ++r) out[(size_t)(r0 + r) * OUT_F + t] = acc[r];
}

// ---------------- launch ----------------

extern "C" void kernel_launch(void* const* d_in, const int* in_sizes, int n_in,
                              void* d_out, int out_size, void* d_ws, size_t ws_size,
                              hipStream_t stream) {
    const float* x     = (const float*)d_in[0];
    const int*   ei    = (const int*)d_in[1];
    const float* eattr = (const float*)d_in[2];
    const float* W_in  = (const float*)d_in[3];
    const float* b_in  = (const float*)d_in[4];
    const float* W_l   = (const float*)d_in[5];
    const float* b_l   = (const float*)d_in[6];
    const float* W_r   = (const float*)d_in[7];
    const float* b_r   = (const float*)d_in[8];
    const float* W_e   = (const float*)d_in[9];
    const float* att   = (const float*)d_in[10];
    const float* bias  = (const float*)d_in[11];
    const float* lnw   = (const float*)d_in[12];
    const float* lnb   = (const float*)d_in[13];
    const float* W_out = (const float*)d_in[14];
    const float* b_out = (const float*)d_in[15];
    float* out = (float*)d_out;

    // workspace layout (~118.5 MB)
    float* h0    = (float*)d_ws;
    float* h1    = h0 + (size_t)N_NODES * HID;
    float* lattr = h1 + (size_t)N_NODES * HID;
    int* rowptr  = (int*)(lattr + (size_t)N_NODES * ED_F);
    int* fill    = rowptr + (N_NODES + 1);
    int* csrsrc  = fill + N_NODES;
    int* csreid  = csrsrc + N_EDGES;
    int* bsum    = csreid + N_EDGES;

    // reuse d_out (N x 256 f32 == exactly 2 x N x 128) as xl/xr scratch;
    // out_kernel fully overwrites it at the end.
    float* xl = out;
    float* xr = out + (size_t)N_NODES * HID;

    const int* srcv = ei;
    const int* dstv = ei + N_EDGES;

    hipMemsetAsync(fill, 0, N_NODES * sizeof(int), stream);
    hist_kernel<<<(N_EDGES + 255) / 256, 256, 0, stream>>>(dstv, fill);
    int nb = (N_NODES + 1023) / 1024;
    scan1_kernel<<<nb, 256, 0, stream>>>(fill, bsum);
    scan2_kernel<<<1, 1, 0, stream>>>(bsum, rowptr, nb);
    scan3_kernel<<<nb, 256, 0, stream>>>(fill, bsum, rowptr);
    hipMemsetAsync(fill, 0, N_NODES * sizeof(int), stream);
    fill_kernel<<<(N_EDGES + 255) / 256, 256, 0, stream>>>(srcv, dstv, rowptr, fill, csrsrc, csreid);
    lattr_kernel<<<(N_NODES * ED_F + 255) / 256, 256, 0, stream>>>(rowptr, csreid, eattr, lattr);

    in_kernel<<<(N_NODES * HID) / 256, 256, 0, stream>>>(x, W_in, b_in, h0);

    float* hc = h0;
    float* hn = h1;
    for (int l = 0; l < LAYERS; ++l) {
        xlr_kernel<<<N_NODES / 16, 128, 0, stream>>>(
            hc, W_l + (size_t)l * HID * HID, b_l + (size_t)l * HID,
            W_r + (size_t)l * HID * HID, b_r + (size_t)l * HID, xl, xr);
        edge_kernel<<<N_NODES, 64, 0, stream>>>(
            xl, xr, hc, hn, rowptr, csrsrc, csreid, eattr, lattr,
            W_e + (size_t)l * ED_F * HID, att + (size_t)l * HEADS * CHN,
            bias + (size_t)l * HID, lnw + (size_t)l * HID, lnb + (size_t)l * HID);
        float* tmp = hc; hc = hn; hn = tmp;
    }

    out_kernel<<<N_NODES / 16, 256, 0, stream>>>(hc, W_out, b_out, out);
}

// Round 2
// 1587.905 us; speedup vs baseline: 1.4285x; 1.4285x over previous
//
#include <hip/hip_runtime.h>
#include <hip/hip_bf16.h>

#define N_NODES 100000
#define N_EDGES 1600000
#define HEADS 4
#define CHN 32
#define HID 128
#define LAYERS 4
#define IN_F 8
#define ED_F 6
#define OUT_F 256
#define NEG_SLOPE 0.2f

__device__ __forceinline__ float elu_f(float x) {
    return x > 0.f ? x : expm1f(x);
}

// ---------------- CSR build ----------------

__global__ void hist_kernel(const int* __restrict__ dst, int* __restrict__ fill) {
    int e = blockIdx.x * blockDim.x + threadIdx.x;
    if (e < N_EDGES) atomicAdd(&fill[dst[e]], 1);
}

__global__ void scan1_kernel(const int* __restrict__ cnt, int* __restrict__ bsum) {
    __shared__ int sd[256];
    int t = threadIdx.x;
    int base = blockIdx.x * 1024 + t * 4;
    int s = 0;
#pragma unroll
    for (int j = 0; j < 4; ++j) {
        int i = base + j;
        if (i < N_NODES) s += cnt[i];
    }
    sd[t] = s;
    for (int off = 128; off > 0; off >>= 1) {
        __syncthreads();
        if (t < off) sd[t] += sd[t + off];
    }
    if (t == 0) bsum[blockIdx.x] = sd[0];
}

__global__ void scan2_kernel(int* __restrict__ bsum, int* __restrict__ rowptr, int nb) {
    int run = 0;
    for (int b = 0; b < nb; ++b) {
        int v = bsum[b];
        bsum[b] = run;
        run += v;
    }
    rowptr[N_NODES] = run;
}

__global__ void scan3_kernel(const int* __restrict__ cnt, const int* __restrict__ bsum,
                             int* __restrict__ rowptr) {
    __shared__ int sd[256];
    int t = threadIdx.x;
    int base = blockIdx.x * 1024 + t * 4;
    int v[4];
#pragma unroll
    for (int j = 0; j < 4; ++j) {
        int i = base + j;
        v[j] = (i < N_NODES) ? cnt[i] : 0;
    }
    int s = v[0] + v[1] + v[2] + v[3];
    sd[t] = s;
    __syncthreads();
    for (int off = 1; off < 256; off <<= 1) {
        int xv = (t >= off) ? sd[t - off] : 0;
        __syncthreads();
        sd[t] += xv;
        __syncthreads();
    }
    int excl = sd[t] - s + bsum[blockIdx.x];
    int pre = 0;
#pragma unroll
    for (int j = 0; j < 4; ++j) {
        int i = base + j;
        if (i < N_NODES) rowptr[i] = excl + pre;
        pre += v[j];
    }
}

__global__ void fill_kernel(const int* __restrict__ src, const int* __restrict__ dst,
                            const int* __restrict__ rowptr, int* __restrict__ fill,
                            int2* __restrict__ csr) {
    int e = blockIdx.x * blockDim.x + threadIdx.x;
    if (e >= N_EDGES) return;
    int d = dst[e];
    int p = rowptr[d] + atomicAdd(&fill[d], 1);
    csr[p] = make_int2(src[e], e);
}

// loop_attr = mean of incoming edge_attr per node (0 if no incoming edges)
__global__ void lattr_kernel(const int* __restrict__ rowptr, const int2* __restrict__ csr,
                             const float* __restrict__ eattr, float* __restrict__ lattr) {
    int gid = blockIdx.x * blockDim.x + threadIdx.x;
    if (gid >= N_NODES * ED_F) return;
    int n = gid / ED_F;
    int d = gid - n * ED_F;
    int rp0 = rowptr[n], rp1 = rowptr[n + 1];
    float s = 0.f;
    for (int p = rp0; p < rp1; ++p) s += eattr[(size_t)csr[p].y * ED_F + d];
    int deg = rp1 - rp0;
    lattr[gid] = s / (float)(deg > 0 ? deg : 1);
}

// ---------------- input MLP: h0 = ELU(x @ W_in + b_in) ----------------

__global__ void in_kernel(const float* __restrict__ x, const float* __restrict__ Wi,
                          const float* __restrict__ bi, float* __restrict__ h0) {
    int gid = blockIdx.x * blockDim.x + threadIdx.x;
    if (gid >= N_NODES * HID) return;
    int n = gid >> 7, j = gid & 127;
    float acc = bi[j];
#pragma unroll
    for (int k = 0; k < IN_F; ++k) acc = fmaf(x[n * IN_F + k], Wi[k * HID + j], acc);
    h0[gid] = elu_f(acc);
}

// ---------------- per-layer node transforms xl = h@Wl+bl, xr = h@Wr+br ----------------

__global__ __launch_bounds__(128) void xlr_kernel(
    const float* __restrict__ h, const float* __restrict__ Wl, const float* __restrict__ bl,
    const float* __restrict__ Wr, const float* __restrict__ br,
    float* __restrict__ xl, float* __restrict__ xr) {
    __shared__ float hs[16][HID];
    int t = threadIdx.x;
    int r0 = blockIdx.x * 16;
#pragma unroll
    for (int r = 0; r < 16; ++r) hs[r][t] = h[(size_t)(r0 + r) * HID + t];
    __syncthreads();
    float accl[16], accr[16];
    float blv = bl[t], brv = br[t];
#pragma unroll
    for (int r = 0; r < 16; ++r) { accl[r] = blv; accr[r] = brv; }
    for (int k = 0; k < HID; ++k) {
        float wl = Wl[k * HID + t];
        float wr = Wr[k * HID + t];
#pragma unroll
        for (int r = 0; r < 16; ++r) {
            float hv = hs[r][k];
            accl[r] = fmaf(hv, wl, accl[r]);
            accr[r] = fmaf(hv, wr, accr[r]);
        }
    }
#pragma unroll
    for (int r = 0; r < 16; ++r) {
        xl[(size_t)(r0 + r) * HID + t] = accl[r];
        xr[(size_t)(r0 + r) * HID + t] = accr[r];
    }
}

// ---------------- fused edge kernel: single-pass softmax-aggregate + LN ----------------
// one wave (64 threads) per node; lane l owns channels 2l, 2l+1 (same head h = l>>4)
// out = (sum_e ex_e * xl[src_e]) / (sum_e ex_e)  -- identical to two-pass softmax
// since no max-subtraction is needed (scores bounded, f32 exp safe).

__device__ __forceinline__ float edge_ex(const float* __restrict__ eat,
                                         const float* __restrict__ xlrow,
                                         const float* we0, const float* we1,
                                         float at0, float at1, float xr0, float xr1,
                                         float2* xls_out) {
    float ea0 = 0.f, ea1 = 0.f;
#pragma unroll
    for (int d = 0; d < ED_F; ++d) {
        float a = eat[d];
        ea0 = fmaf(a, we0[d], ea0);
        ea1 = fmaf(a, we1[d], ea1);
    }
    float2 xls = *(const float2*)xlrow;
    float m0 = xls.x + xr0 + ea0;
    float m1 = xls.y + xr1 + ea1;
    m0 = m0 > 0.f ? m0 : NEG_SLOPE * m0;
    m1 = m1 > 0.f ? m1 : NEG_SLOPE * m1;
    float t = m0 * at0 + m1 * at1;
    // reduce across the 16 lanes of this head (32 channels)
    t += __shfl_xor(t, 1);
    t += __shfl_xor(t, 2);
    t += __shfl_xor(t, 4);
    t += __shfl_xor(t, 8);
    *xls_out = xls;
    return expf(t);
}

__global__ __launch_bounds__(64) void edge_kernel(
    const float* __restrict__ xl, const float* __restrict__ xr,
    const float* __restrict__ hcur, float* __restrict__ hnext,
    const int* __restrict__ rowptr, const int2* __restrict__ csr,
    const float* __restrict__ eattr, const float* __restrict__ lattr,
    const float* __restrict__ We, const float* __restrict__ att,
    const float* __restrict__ bias_l, const float* __restrict__ lnw,
    const float* __restrict__ lnb) {
    int v = blockIdx.x;
    int lane = threadIdx.x;
    int c0 = lane * 2;

    float we0[ED_F], we1[ED_F];
#pragma unroll
    for (int d = 0; d < ED_F; ++d) {
        we0[d] = We[d * HID + c0];
        we1[d] = We[d * HID + c0 + 1];
    }
    float at0 = att[c0], at1 = att[c0 + 1];
    float xr0 = xr[(size_t)v * HID + c0];
    float xr1 = xr[(size_t)v * HID + c0 + 1];
    int rp0 = rowptr[v], rp1 = rowptr[v + 1];

    // single pass: numerator (acc) and denominator together
    float2 xlv;
    float ex_self = edge_ex(lattr + (size_t)v * ED_F, xl + (size_t)v * HID + c0,
                            we0, we1, at0, at1, xr0, xr1, &xlv);
    float denom = ex_self;
    float acc0 = ex_self * xlv.x;
    float acc1 = ex_self * xlv.y;
    for (int p = rp0; p < rp1; ++p) {
        int2 se = csr[p];
        float2 xls;
        float ex = edge_ex(eattr + (size_t)se.y * ED_F, xl + (size_t)se.x * HID + c0,
                           we0, we1, at0, at1, xr0, xr1, &xls);
        denom += ex;
        acc0 = fmaf(ex, xls.x, acc0);
        acc1 = fmaf(ex, xls.y, acc1);
    }
    float rd = 1.f / denom;
    acc0 *= rd;
    acc1 *= rd;

    // ---- epilogue: bias + residual + LayerNorm + ELU
    float res0 = hcur[(size_t)v * HID + c0];
    float res1 = hcur[(size_t)v * HID + c0 + 1];
    float y0 = acc0 + bias_l[c0] + res0;
    float y1 = acc1 + bias_l[c0 + 1] + res1;
    float s = y0 + y1;
    float sq = y0 * y0 + y1 * y1;
#pragma unroll
    for (int off = 1; off < 64; off <<= 1) {
        s += __shfl_xor(s, off);
        sq += __shfl_xor(sq, off);
    }
    float mu = s * (1.f / HID);
    float var = sq * (1.f / HID) - mu * mu;
    float rstd = rsqrtf(var + 1e-5f);
    float n0 = (y0 - mu) * rstd * lnw[c0] + lnb[c0];
    float n1 = (y1 - mu) * rstd * lnw[c0 + 1] + lnb[c0 + 1];
    float2 o;
    o.x = elu_f(n0);
    o.y = elu_f(n1);
    *(float2*)(hnext + (size_t)v * HID + c0) = o;
}

// ---------------- output GEMM: out = h @ W_out + b_out ----------------

__global__ __launch_bounds__(256) void out_kernel(const float* __restrict__ h,
                                                  const float* __restrict__ Wo,
                                                  const float* __restrict__ bo,
                                                  float* __restrict__ out) {
    __shared__ float hs[16][HID];
    int t = threadIdx.x;
    int r0 = blockIdx.x * 16;
    for (int idx = t; idx < 16 * HID; idx += 256)
        hs[idx >> 7][idx & 127] = h[(size_t)r0 * HID + idx];
    __syncthreads();
    float acc[16];
    float bv = bo[t];
#pragma unroll
    for (int r = 0; r < 16; ++r) acc[r] = bv;
    for (int k = 0; k < HID; ++k) {
        float w = Wo[k * OUT_F + t];
#pragma unroll
        for (int r = 0; r < 16; ++r) acc[r] = fmaf(hs[r][k], w, acc[r]);
    }
#pragma unroll
    for (int r = 0; r < 16; ++r) out[(size_t)(r0 + r) * OUT_F + t] = acc[r];
}

// ---------------- launch ----------------

extern "C" void kernel_launch(void* const* d_in, const int* in_sizes, int n_in,
                              void* d_out, int out_size, void* d_ws, size_t ws_size,
                              hipStream_t stream) {
    const float* x     = (const float*)d_in[0];
    const int*   ei    = (const int*)d_in[1];
    const float* eattr = (const float*)d_in[2];
    const float* W_in  = (const float*)d_in[3];
    const float* b_in  = (const float*)d_in[4];
    const float* W_l   = (const float*)d_in[5];
    const float* b_l   = (const float*)d_in[6];
    const float* W_r   = (const float*)d_in[7];
    const float* b_r   = (const float*)d_in[8];
    const float* W_e   = (const float*)d_in[9];
    const float* att   = (const float*)d_in[10];
    const float* bias  = (const float*)d_in[11];
    const float* lnw   = (const float*)d_in[12];
    const float* lnb   = (const float*)d_in[13];
    const float* W_out = (const float*)d_in[14];
    const float* b_out = (const float*)d_in[15];
    float* out = (float*)d_out;

    // workspace layout
    float* h0    = (float*)d_ws;
    float* h1    = h0 + (size_t)N_NODES * HID;
    float* lattr = h1 + (size_t)N_NODES * HID;
    int* rowptr  = (int*)(lattr + (size_t)N_NODES * ED_F);
    int* fill    = rowptr + (N_NODES + 1);
    int2* csr    = (int2*)(fill + N_NODES);
    int* bsum    = (int*)(csr + N_EDGES);

    // reuse d_out (N x 256 f32 == exactly 2 x N x 128) as xl/xr scratch;
    // out_kernel fully overwrites it at the end.
    float* xl = out;
    float* xr = out + (size_t)N_NODES * HID;

    const int* srcv = ei;
    const int* dstv = ei + N_EDGES;

    hipMemsetAsync(fill, 0, N_NODES * sizeof(int), stream);
    hist_kernel<<<(N_EDGES + 255) / 256, 256, 0, stream>>>(dstv, fill);
    int nb = (N_NODES + 1023) / 1024;
    scan1_kernel<<<nb, 256, 0, stream>>>(fill, bsum);
    scan2_kernel<<<1, 1, 0, stream>>>(bsum, rowptr, nb);
    scan3_kernel<<<nb, 256, 0, stream>>>(fill, bsum, rowptr);
    hipMemsetAsync(fill, 0, N_NODES * sizeof(int), stream);
    fill_kernel<<<(N_EDGES + 255) / 256, 256, 0, stream>>>(srcv, dstv, rowptr, fill, csr);
    lattr_kernel<<<(N_NODES * ED_F + 255) / 256, 256, 0, stream>>>(rowptr, csr, eattr, lattr);

    in_kernel<<<(N_NODES * HID) / 256, 256, 0, stream>>>(x, W_in, b_in, h0);

    float* hc = h0;
    float* hn = h1;
    for (int l = 0; l < LAYERS; ++l) {
        xlr_kernel<<<N_NODES / 16, 128, 0, stream>>>(
            hc, W_l + (size_t)l * HID * HID, b_l + (size_t)l * HID,
            W_r + (size_t)l * HID * HID, b_r + (size_t)l * HID, xl, xr);
        edge_kernel<<<N_NODES, 64, 0, stream>>>(
            xl, xr, hc, hn, rowptr, csr, eattr, lattr,
            W_e + (size_t)l * ED_F * HID, att + (size_t)l * HEADS * CHN,
            bias + (size_t)l * HID, lnw + (size_t)l * HID, lnb + (size_t)l * HID);
        float* tmp = hc; hc = hn; hn = tmp;
    }

    out_kernel<<<N_NODES / 16, 256, 0, stream>>>(hc, W_out, b_out, out);
}